// Round 11
// baseline (93.949 us; speedup 1.0000x reference)
//
#include <hip/hip_runtime.h>

// DIN attention pooling — round 11: 1-wave blocks, fully-resident grid.
//   Wb[e][h] = (W1b-W1c)[e][h] + q_e*W1d[e][h];  qh[h] = b1[h] + q @ (W1a+W1c)
//   H = sig(K@Wb + qh); G = sig(H@W2 + b2); s = G@W3 + b3 (masked); out = s^T K
// Evidence R7/R9/R10: ~70us, VALU ~45%, ~2.2 waves/SIMD effective — latency-
// bound on dependent sigmoid/MFMA chains with too few resident waves.
// R11: block=64 (one wave), wave=(b,half), grid=4096 => 16 waves/CU (4/SIMD),
// whole grid resident, no barriers, no block turnover. W2 per-tile from
// global (L1-hot). Halves merge via atomicAdd (d_out pre-zeroed on stream).
// Register discipline: launch_bounds(64,4) caps 128; R9 live set measured 84.

constexpr int Bn = 2048, Tn = 200, En = 64;
constexpr int HS_W  = 84;                // H slab stride (f16), conflict-free
constexpr int HSLAB = 16 * HS_W + 48;    // 1392: covers row-15 aH2 read to 1388

typedef _Float16 f16;
typedef _Float16 f16x8 __attribute__((ext_vector_type(8)));
typedef float f32x4 __attribute__((ext_vector_type(4)));

__device__ __align__(16) f16 g_wkf[80 * 64];    // [h][e]  W1b - W1c
__device__ __align__(16) f16 g_wqf[80 * 64];    // [h][e]  W1d
__device__ __align__(16) f16 g_wsumT[80 * 64];  // [h][e]  W1a + W1c
__device__ __align__(16) f16 g_w2t[48 * 96];    // [j][h]  W2^T, zeros j>=40 or h>=80

__device__ __forceinline__ float fsig(float x) {
  return __fdividef(1.0f, 1.0f + __expf(-x));
}

__global__ __launch_bounds__(256) void din_prep(const float* __restrict__ W1,
                                                const float* __restrict__ W2) {
  int idx = blockIdx.x * 256 + threadIdx.x;   // grid 20 -> 5120
  if (idx < 5120) {
    int h = idx >> 6, e = idx & 63;
    float wa = W1[e * 80 + h], wb = W1[(64 + e) * 80 + h];
    float wc = W1[(128 + e) * 80 + h], wd = W1[(192 + e) * 80 + h];
    g_wkf[idx] = (f16)(wb - wc);
    g_wqf[idx] = (f16)wd;
    g_wsumT[idx] = (f16)(wa + wc);
  }
  if (idx < 4608) {
    int j = idx / 96, h = idx - j * 96;
    g_w2t[idx] = (h < 80 && j < 40) ? (f16)W2[h * 40 + j] : (f16)0.0f;
  }
}

__global__ __launch_bounds__(64, 4) void din_main(
    const float* __restrict__ query,
    const float* __restrict__ keys,
    const int*   __restrict__ keys_length,
    const float* __restrict__ b1,
    const float* __restrict__ b2,
    const float* __restrict__ W3,
    const float* __restrict__ b3,
    float* __restrict__ out)
{
  __shared__ __align__(16) f16 hs[HSLAB];   // 2,784 B (one wave per block)
  __shared__ float sSw[16];                 //     64 B

  const int lane = threadIdx.x;
  const int l15 = lane & 15;
  const int l4  = lane >> 4;

  const int b    = blockIdx.x >> 1;
  const int half = blockIdx.x & 1;
  const int mts  = half ? 7 : 0;
  const int mte  = half ? 13 : 7;

  const float* qp = query + (size_t)b * En;
  const float* kb = keys + (size_t)b * Tn * En;
  const int len = keys_length[b];
  const float b3v = b3[0];

  // ---- zero slab (cols 80..95 + pad must read 0.0 in L2 MFMAs) ----
  const f16x8 zf = (f16x8)(f16)0.0f;
  for (int i = lane * 8; i < HSLAB; i += 512) *(f16x8*)&hs[i] = zf;

  // ---- q fragments (f16) ----
  f16x8 qf0, qf1;
  {
    float4 qa = *(const float4*)(qp + l4 * 8);
    float4 qb = *(const float4*)(qp + l4 * 8 + 4);
    float4 qc = *(const float4*)(qp + 32 + l4 * 8);
    float4 qd = *(const float4*)(qp + 32 + l4 * 8 + 4);
    qf0 = (f16x8){(f16)qa.x,(f16)qa.y,(f16)qa.z,(f16)qa.w,
                  (f16)qb.x,(f16)qb.y,(f16)qb.z,(f16)qb.w};
    qf1 = (f16x8){(f16)qc.x,(f16)qc.y,(f16)qc.z,(f16)qc.w,
                  (f16)qd.x,(f16)qd.y,(f16)qd.z,(f16)qd.w};
  }

  // ---- qh[c] = b1[c] + q @ wsum[:,c] via VALU dot + shfl over l4 ----
  float qhv[5];
  #pragma unroll
  for (int n = 0; n < 5; ++n) {
    int c = n * 16 + l15;
    f16x8 ws0 = *(const f16x8*)&g_wsumT[c * 64 + l4 * 8];
    f16x8 ws1 = *(const f16x8*)&g_wsumT[c * 64 + 32 + l4 * 8];
    float p = 0.f;
    #pragma unroll
    for (int j = 0; j < 8; ++j)
      p += (float)qf0[j] * (float)ws0[j] + (float)qf1[j] * (float)ws1[j];
    p += __shfl_xor(p, 16, 64);
    p += __shfl_xor(p, 32, 64);
    qhv[n] = p + b1[c];
  }

  // ---- L1 B-fragments: Wb = wk + q*wqk (elementwise f16) ----
  f16x8 bf0[5], bf1[5];
  #pragma unroll
  for (int n = 0; n < 5; ++n) {
    int c = n * 16 + l15;
    bf0[n] = *(const f16x8*)&g_wkf[c * 64 + l4 * 8]
           + qf0 * *(const f16x8*)&g_wqf[c * 64 + l4 * 8];
    bf1[n] = *(const f16x8*)&g_wkf[c * 64 + 32 + l4 * 8]
           + qf1 * *(const f16x8*)&g_wqf[c * 64 + 32 + l4 * 8];
  }

  // ---- per-col constants for L2/L3 ----
  float b2v[3], w3v[3];
  #pragma unroll
  for (int n = 0; n < 3; ++n) {
    int c = n * 16 + l15;
    b2v[n] = (c < 40) ? b2[c] : 0.0f;
    w3v[n] = (c < 40) ? W3[c] : 0.0f;
  }

  float poolA[8] = {0,0,0,0,0,0,0,0};
  float poolB[8] = {0,0,0,0,0,0,0,0};

  // ---- prefetch first tile's keys rows ----
  float4 p0, p1, p2, p3;
  {
    int r = mts * 16 + l15; const float* kr = kb + (r < Tn ? r : Tn - 1) * 64;
    p0 = *(const float4*)(kr + l4 * 8);
    p1 = *(const float4*)(kr + l4 * 8 + 4);
    p2 = *(const float4*)(kr + 32 + l4 * 8);
    p3 = *(const float4*)(kr + 32 + l4 * 8 + 4);
  }

  for (int mt = mts; mt < mte; ++mt) {
    f16x8 ka = (f16x8){(f16)p0.x,(f16)p0.y,(f16)p0.z,(f16)p0.w,
                       (f16)p1.x,(f16)p1.y,(f16)p1.z,(f16)p1.w};
    f16x8 kc = (f16x8){(f16)p2.x,(f16)p2.y,(f16)p2.z,(f16)p2.w,
                       (f16)p3.x,(f16)p3.y,(f16)p3.z,(f16)p3.w};
    // issue next tile's loads under this tile's compute
    if (mt + 1 < mte) {
      int r = (mt + 1) * 16 + l15; const float* kr = kb + (r < Tn ? r : Tn - 1) * 64;
      p0 = *(const float4*)(kr + l4 * 8);
      p1 = *(const float4*)(kr + l4 * 8 + 4);
      p2 = *(const float4*)(kr + 32 + l4 * 8);
      p3 = *(const float4*)(kr + 32 + l4 * 8 + 4);
    }

    // L1 + sigmoid -> H slab, per n (acc liveness = 4)
    #pragma unroll
    for (int n = 0; n < 5; ++n) {
      f32x4 acc = {0.f, 0.f, 0.f, 0.f};
      acc = __builtin_amdgcn_mfma_f32_16x16x32_f16(ka, bf0[n], acc, 0, 0, 0);
      acc = __builtin_amdgcn_mfma_f32_16x16x32_f16(kc, bf1[n], acc, 0, 0, 0);
      int c = n * 16 + l15;
      #pragma unroll
      for (int i = 0; i < 4; ++i)
        hs[(l4 * 4 + i) * HS_W + c] = (f16)fsig(acc[i] + qhv[n]);
    }
    // H^T A-frags
    f16x8 aH0 = *(const f16x8*)&hs[l15 * HS_W + l4 * 8];
    f16x8 aH1 = *(const f16x8*)&hs[l15 * HS_W + 32 + l4 * 8];
    f16x8 aH2 = *(const f16x8*)&hs[l15 * HS_W + 64 + l4 * 8];

    // L2 (B-frags from global g_w2t, L1-cache-hot) + sigmoid + W3 dot
    float sc[4] = {0.f, 0.f, 0.f, 0.f};
    #pragma unroll
    for (int n = 0; n < 3; ++n) {
      int c = n * 16 + l15;
      f32x4 acc = {0.f, 0.f, 0.f, 0.f};
      acc = __builtin_amdgcn_mfma_f32_16x16x32_f16(aH0, *(const f16x8*)&g_w2t[c * 96 + l4 * 8], acc, 0, 0, 0);
      acc = __builtin_amdgcn_mfma_f32_16x16x32_f16(aH1, *(const f16x8*)&g_w2t[c * 96 + 32 + l4 * 8], acc, 0, 0, 0);
      acc = __builtin_amdgcn_mfma_f32_16x16x32_f16(aH2, *(const f16x8*)&g_w2t[c * 96 + 64 + l4 * 8], acc, 0, 0, 0);
      #pragma unroll
      for (int i = 0; i < 4; ++i)
        sc[i] += fsig(acc[i] + b2v[n]) * w3v[n];
    }
    // reduce score over the 16 cols held across l15
    #pragma unroll
    for (int m = 1; m < 16; m <<= 1) {
      #pragma unroll
      for (int i = 0; i < 4; ++i) sc[i] += __shfl_xor(sc[i], m, 64);
    }
    if (l15 == 0) {
      #pragma unroll
      for (int i = 0; i < 4; ++i) {
        int rr = mt * 16 + l4 * 4 + i;
        sSw[l4 * 4 + i] = (rr < len) ? sc[i] + b3v : 0.0f;
      }
    }
    // broadcast this lane's row score (same-wave LDS, in-order per wave)
    float sv = sSw[l15];
    #pragma unroll
    for (int j = 0; j < 8; ++j) {
      poolA[j] += sv * (float)ka[j];
      poolB[j] += sv * (float)kc[j];
    }
  }

  // ---- reduce pooling over the 16 rows (l15) of each l4 group ----
  #pragma unroll
  for (int m = 1; m < 16; m <<= 1) {
    #pragma unroll
    for (int j = 0; j < 8; ++j) {
      poolA[j] += __shfl_xor(poolA[j], m, 64);
      poolB[j] += __shfl_xor(poolB[j], m, 64);
    }
  }
  if (l15 == 0) {
    float* ob = out + (size_t)b * En;
    #pragma unroll
    for (int j = 0; j < 8; ++j) {
      atomicAdd(&ob[l4 * 8 + j], poolA[j]);
      atomicAdd(&ob[32 + l4 * 8 + j], poolB[j]);
    }
  }
}

extern "C" void kernel_launch(void* const* d_in, const int* in_sizes, int n_in,
                              void* d_out, int out_size, void* d_ws, size_t ws_size,
                              hipStream_t stream) {
  const float* query       = (const float*)d_in[0];
  const float* keys        = (const float*)d_in[1];
  const int*   keys_length = (const int*)d_in[2];
  const float* W1 = (const float*)d_in[3];
  const float* b1 = (const float*)d_in[4];
  const float* W2 = (const float*)d_in[5];
  const float* b2 = (const float*)d_in[6];
  const float* W3 = (const float*)d_in[7];
  const float* b3 = (const float*)d_in[8];
  float* out = (float*)d_out;

  hipMemsetAsync(out, 0, (size_t)Bn * En * sizeof(float), stream);
  hipLaunchKernelGGL(din_prep, dim3(20), dim3(256), 0, stream, W1, W2);
  hipLaunchKernelGGL(din_main, dim3(Bn * 2), dim3(64), 0, stream,
                     query, keys, keys_length, b1, b2, W3, b3, out);
}

// Round 12
// 64.615 us; speedup vs baseline: 1.4540x; 1.4540x over previous
//
#include <hip/hip_runtime.h>

// DIN attention pooling — round 12: R11 structure, register class fixed.
//   Wb[e][h] = (W1b-W1c)[e][h] + q_e*W1d[e][h];  qh[h] = b1[h] + q @ (W1a+W1c)
//   H = sig(K@Wb + qh); G = sig(H@W2 + b2); s = G@W3 + b3 (masked); out = s^T K
// REGISTER LAW (R6/R8/R11 vs R7/R9): waves/EU bound >=4 (budget 128) =>
// compiler pins VGPR=64 and spills this live set (~50MB scratch writes);
// bound 3 (budget 170) => spill-free. Always use the 170-reg class.
// Structure: block=64 (one wave), wave=(b,half), grid=4096, no barriers,
// no block turnover. W2 per-tile from global (L1-hot). atomicAdd merge.

constexpr int Bn = 2048, Tn = 200, En = 64;
constexpr int HS_W  = 84;                // H slab stride (f16), conflict-free
constexpr int HSLAB = 16 * HS_W + 48;    // 1392: covers row-15 aH2 read to 1388

typedef _Float16 f16;
typedef _Float16 f16x8 __attribute__((ext_vector_type(8)));
typedef float f32x4 __attribute__((ext_vector_type(4)));

__device__ __align__(16) f16 g_wkf[80 * 64];    // [h][e]  W1b - W1c
__device__ __align__(16) f16 g_wqf[80 * 64];    // [h][e]  W1d
__device__ __align__(16) f16 g_wsumT[80 * 64];  // [h][e]  W1a + W1c
__device__ __align__(16) f16 g_w2t[48 * 96];    // [j][h]  W2^T, zeros j>=40 or h>=80

__device__ __forceinline__ float fsig(float x) {
  return __fdividef(1.0f, 1.0f + __expf(-x));
}

__global__ __launch_bounds__(256) void din_prep(const float* __restrict__ W1,
                                                const float* __restrict__ W2) {
  int idx = blockIdx.x * 256 + threadIdx.x;   // grid 20 -> 5120
  if (idx < 5120) {
    int h = idx >> 6, e = idx & 63;
    float wa = W1[e * 80 + h], wb = W1[(64 + e) * 80 + h];
    float wc = W1[(128 + e) * 80 + h], wd = W1[(192 + e) * 80 + h];
    g_wkf[idx] = (f16)(wb - wc);
    g_wqf[idx] = (f16)wd;
    g_wsumT[idx] = (f16)(wa + wc);
  }
  if (idx < 4608) {
    int j = idx / 96, h = idx - j * 96;
    g_w2t[idx] = (h < 80 && j < 40) ? (f16)W2[h * 40 + j] : (f16)0.0f;
  }
}

__global__ __launch_bounds__(64, 3) void din_main(
    const float* __restrict__ query,
    const float* __restrict__ keys,
    const int*   __restrict__ keys_length,
    const float* __restrict__ b1,
    const float* __restrict__ b2,
    const float* __restrict__ W3,
    const float* __restrict__ b3,
    float* __restrict__ out)
{
  __shared__ __align__(16) f16 hs[HSLAB];   // 2,784 B (one wave per block)
  __shared__ float sSw[16];                 //     64 B

  const int lane = threadIdx.x;
  const int l15 = lane & 15;
  const int l4  = lane >> 4;

  const int b    = blockIdx.x >> 1;
  const int half = blockIdx.x & 1;
  const int mts  = half ? 7 : 0;
  const int mte  = half ? 13 : 7;

  const float* qp = query + (size_t)b * En;
  const float* kb = keys + (size_t)b * Tn * En;
  const int len = keys_length[b];
  const float b3v = b3[0];

  // ---- zero slab (cols 80..95 + pad must read 0.0 in L2 MFMAs) ----
  const f16x8 zf = (f16x8)(f16)0.0f;
  for (int i = lane * 8; i < HSLAB; i += 512) *(f16x8*)&hs[i] = zf;

  // ---- q fragments (f16) ----
  f16x8 qf0, qf1;
  {
    float4 qa = *(const float4*)(qp + l4 * 8);
    float4 qb = *(const float4*)(qp + l4 * 8 + 4);
    float4 qc = *(const float4*)(qp + 32 + l4 * 8);
    float4 qd = *(const float4*)(qp + 32 + l4 * 8 + 4);
    qf0 = (f16x8){(f16)qa.x,(f16)qa.y,(f16)qa.z,(f16)qa.w,
                  (f16)qb.x,(f16)qb.y,(f16)qb.z,(f16)qb.w};
    qf1 = (f16x8){(f16)qc.x,(f16)qc.y,(f16)qc.z,(f16)qc.w,
                  (f16)qd.x,(f16)qd.y,(f16)qd.z,(f16)qd.w};
  }

  // ---- qh[c] = b1[c] + q @ wsum[:,c] via VALU dot + shfl over l4 ----
  float qhv[5];
  #pragma unroll
  for (int n = 0; n < 5; ++n) {
    int c = n * 16 + l15;
    f16x8 ws0 = *(const f16x8*)&g_wsumT[c * 64 + l4 * 8];
    f16x8 ws1 = *(const f16x8*)&g_wsumT[c * 64 + 32 + l4 * 8];
    float p = 0.f;
    #pragma unroll
    for (int j = 0; j < 8; ++j)
      p += (float)qf0[j] * (float)ws0[j] + (float)qf1[j] * (float)ws1[j];
    p += __shfl_xor(p, 16, 64);
    p += __shfl_xor(p, 32, 64);
    qhv[n] = p + b1[c];
  }

  // ---- L1 B-fragments: Wb = wk + q*wqk (elementwise f16) ----
  f16x8 bf0[5], bf1[5];
  #pragma unroll
  for (int n = 0; n < 5; ++n) {
    int c = n * 16 + l15;
    bf0[n] = *(const f16x8*)&g_wkf[c * 64 + l4 * 8]
           + qf0 * *(const f16x8*)&g_wqf[c * 64 + l4 * 8];
    bf1[n] = *(const f16x8*)&g_wkf[c * 64 + 32 + l4 * 8]
           + qf1 * *(const f16x8*)&g_wqf[c * 64 + 32 + l4 * 8];
  }

  // ---- per-col constants for L2/L3 ----
  float b2v[3], w3v[3];
  #pragma unroll
  for (int n = 0; n < 3; ++n) {
    int c = n * 16 + l15;
    b2v[n] = (c < 40) ? b2[c] : 0.0f;
    w3v[n] = (c < 40) ? W3[c] : 0.0f;
  }

  float poolA[8] = {0,0,0,0,0,0,0,0};
  float poolB[8] = {0,0,0,0,0,0,0,0};

  // ---- prefetch first tile's keys rows ----
  float4 p0, p1, p2, p3;
  {
    int r = mts * 16 + l15; const float* kr = kb + (r < Tn ? r : Tn - 1) * 64;
    p0 = *(const float4*)(kr + l4 * 8);
    p1 = *(const float4*)(kr + l4 * 8 + 4);
    p2 = *(const float4*)(kr + 32 + l4 * 8);
    p3 = *(const float4*)(kr + 32 + l4 * 8 + 4);
  }

  for (int mt = mts; mt < mte; ++mt) {
    f16x8 ka = (f16x8){(f16)p0.x,(f16)p0.y,(f16)p0.z,(f16)p0.w,
                       (f16)p1.x,(f16)p1.y,(f16)p1.z,(f16)p1.w};
    f16x8 kc = (f16x8){(f16)p2.x,(f16)p2.y,(f16)p2.z,(f16)p2.w,
                       (f16)p3.x,(f16)p3.y,(f16)p3.z,(f16)p3.w};
    // issue next tile's loads under this tile's compute
    if (mt + 1 < mte) {
      int r = (mt + 1) * 16 + l15; const float* kr = kb + (r < Tn ? r : Tn - 1) * 64;
      p0 = *(const float4*)(kr + l4 * 8);
      p1 = *(const float4*)(kr + l4 * 8 + 4);
      p2 = *(const float4*)(kr + 32 + l4 * 8);
      p3 = *(const float4*)(kr + 32 + l4 * 8 + 4);
    }

    // L1 + sigmoid -> H slab, per n (acc liveness = 4)
    #pragma unroll
    for (int n = 0; n < 5; ++n) {
      f32x4 acc = {0.f, 0.f, 0.f, 0.f};
      acc = __builtin_amdgcn_mfma_f32_16x16x32_f16(ka, bf0[n], acc, 0, 0, 0);
      acc = __builtin_amdgcn_mfma_f32_16x16x32_f16(kc, bf1[n], acc, 0, 0, 0);
      int c = n * 16 + l15;
      #pragma unroll
      for (int i = 0; i < 4; ++i)
        hs[(l4 * 4 + i) * HS_W + c] = (f16)fsig(acc[i] + qhv[n]);
    }
    // H^T A-frags
    f16x8 aH0 = *(const f16x8*)&hs[l15 * HS_W + l4 * 8];
    f16x8 aH1 = *(const f16x8*)&hs[l15 * HS_W + 32 + l4 * 8];
    f16x8 aH2 = *(const f16x8*)&hs[l15 * HS_W + 64 + l4 * 8];

    // L2 (B-frags from global g_w2t, L1-cache-hot) + sigmoid + W3 dot
    float sc[4] = {0.f, 0.f, 0.f, 0.f};
    #pragma unroll
    for (int n = 0; n < 3; ++n) {
      int c = n * 16 + l15;
      f32x4 acc = {0.f, 0.f, 0.f, 0.f};
      acc = __builtin_amdgcn_mfma_f32_16x16x32_f16(aH0, *(const f16x8*)&g_w2t[c * 96 + l4 * 8], acc, 0, 0, 0);
      acc = __builtin_amdgcn_mfma_f32_16x16x32_f16(aH1, *(const f16x8*)&g_w2t[c * 96 + 32 + l4 * 8], acc, 0, 0, 0);
      acc = __builtin_amdgcn_mfma_f32_16x16x32_f16(aH2, *(const f16x8*)&g_w2t[c * 96 + 64 + l4 * 8], acc, 0, 0, 0);
      #pragma unroll
      for (int i = 0; i < 4; ++i)
        sc[i] += fsig(acc[i] + b2v[n]) * w3v[n];
    }
    // reduce score over the 16 cols held across l15
    #pragma unroll
    for (int m = 1; m < 16; m <<= 1) {
      #pragma unroll
      for (int i = 0; i < 4; ++i) sc[i] += __shfl_xor(sc[i], m, 64);
    }
    if (l15 == 0) {
      #pragma unroll
      for (int i = 0; i < 4; ++i) {
        int rr = mt * 16 + l4 * 4 + i;
        sSw[l4 * 4 + i] = (rr < len) ? sc[i] + b3v : 0.0f;
      }
    }
    // broadcast this lane's row score (same-wave LDS, in-order per wave)
    float sv = sSw[l15];
    #pragma unroll
    for (int j = 0; j < 8; ++j) {
      poolA[j] += sv * (float)ka[j];
      poolB[j] += sv * (float)kc[j];
    }
  }

  // ---- reduce pooling over the 16 rows (l15) of each l4 group ----
  #pragma unroll
  for (int m = 1; m < 16; m <<= 1) {
    #pragma unroll
    for (int j = 0; j < 8; ++j) {
      poolA[j] += __shfl_xor(poolA[j], m, 64);
      poolB[j] += __shfl_xor(poolB[j], m, 64);
    }
  }
  if (l15 == 0) {
    float* ob = out + (size_t)b * En;
    #pragma unroll
    for (int j = 0; j < 8; ++j) {
      atomicAdd(&ob[l4 * 8 + j], poolA[j]);
      atomicAdd(&ob[32 + l4 * 8 + j], poolB[j]);
    }
  }
}

extern "C" void kernel_launch(void* const* d_in, const int* in_sizes, int n_in,
                              void* d_out, int out_size, void* d_ws, size_t ws_size,
                              hipStream_t stream) {
  const float* query       = (const float*)d_in[0];
  const float* keys        = (const float*)d_in[1];
  const int*   keys_length = (const int*)d_in[2];
  const float* W1 = (const float*)d_in[3];
  const float* b1 = (const float*)d_in[4];
  const float* W2 = (const float*)d_in[5];
  const float* b2 = (const float*)d_in[6];
  const float* W3 = (const float*)d_in[7];
  const float* b3 = (const float*)d_in[8];
  float* out = (float*)d_out;

  hipMemsetAsync(out, 0, (size_t)Bn * En * sizeof(float), stream);
  hipLaunchKernelGGL(din_prep, dim3(20), dim3(256), 0, stream, W1, W2);
  hipLaunchKernelGGL(din_main, dim3(Bn * 2), dim3(64), 0, stream,
                     query, keys, keys_length, b1, b2, W3, b3, out);
}

// Round 13
// 58.668 us; speedup vs baseline: 1.6014x; 1.1014x over previous
//
#include <hip/hip_runtime.h>

// DIN attention pooling — round 13: R12 + DPP row-reductions + packed cvt.
//   Wb[e][h] = (W1b-W1c)[e][h] + q_e*W1d[e][h];  qh[h] = b1[h] + q @ (W1a+W1c)
//   H = sig(K@Wb + qh); G = sig(H@W2 + b2); s = G@W3 + b3 (masked); out = s^T K
// Plateau R7/R9/R10/R12: ~65-70us, VALU ~47%, ~8 waves/CU regardless of WG
// shape => per-wave serial latency is the lever. All reduce masks are 1,2,4,8
// (row16-local): __shfl_xor (ds_bpermute, ~30cyc, LDS pipe) -> DPP row_ror
// adds (VALU, ~4-8cyc). f32->f16 frag packing via v_cvt_pkrtz (16 cvt -> 8).
// REGISTER LAW (R6/R8/R11 vs R7/R9/R12): unified budget must be the 170-reg
// class (min-waves/EU = 3); budget 128 pins VGPR=64 and spills ~50MB.

constexpr int Bn = 2048, Tn = 200, En = 64;
constexpr int HS_W  = 84;                // H slab stride (f16), conflict-free
constexpr int HSLAB = 16 * HS_W + 48;    // 1392: covers row-15 aH2 read to 1388

typedef _Float16 f16;
typedef _Float16 f16x2 __attribute__((ext_vector_type(2)));
typedef _Float16 f16x8 __attribute__((ext_vector_type(8)));
typedef float f32x4 __attribute__((ext_vector_type(4)));

__device__ __align__(16) f16 g_wkf[80 * 64];    // [h][e]  W1b - W1c
__device__ __align__(16) f16 g_wqf[80 * 64];    // [h][e]  W1d
__device__ __align__(16) f16 g_wsumT[80 * 64];  // [h][e]  W1a + W1c
__device__ __align__(16) f16 g_w2t[48 * 96];    // [j][h]  W2^T, zeros j>=40 or h>=80

__device__ __forceinline__ float fsig(float x) {
  return __fdividef(1.0f, 1.0f + __expf(-x));
}

// DPP row_ror:N add (N=1,2,4,8): rotate within 16-lane row, pure VALU.
template <int CTRL>
__device__ __forceinline__ float dpp_add(float x) {
  int y = __builtin_amdgcn_update_dpp(0, __builtin_bit_cast(int, x),
                                      CTRL, 0xf, 0xf, true);
  return x + __builtin_bit_cast(float, y);
}
// full sum over the 16-lane row, result in every lane (ror 1,2,4,8)
__device__ __forceinline__ float row16_sum(float x) {
  x = dpp_add<0x121>(x);
  x = dpp_add<0x122>(x);
  x = dpp_add<0x124>(x);
  x = dpp_add<0x128>(x);
  return x;
}

__device__ __forceinline__ f16x8 pack8(float4 a, float4 b) {
  union { f16x2 p[4]; f16x8 v; } u;
  u.p[0] = __builtin_bit_cast(f16x2, __builtin_amdgcn_cvt_pkrtz(a.x, a.y));
  u.p[1] = __builtin_bit_cast(f16x2, __builtin_amdgcn_cvt_pkrtz(a.z, a.w));
  u.p[2] = __builtin_bit_cast(f16x2, __builtin_amdgcn_cvt_pkrtz(b.x, b.y));
  u.p[3] = __builtin_bit_cast(f16x2, __builtin_amdgcn_cvt_pkrtz(b.z, b.w));
  return u.v;
}

__global__ __launch_bounds__(256) void din_prep(const float* __restrict__ W1,
                                                const float* __restrict__ W2) {
  int idx = blockIdx.x * 256 + threadIdx.x;   // grid 20 -> 5120
  if (idx < 5120) {
    int h = idx >> 6, e = idx & 63;
    float wa = W1[e * 80 + h], wb = W1[(64 + e) * 80 + h];
    float wc = W1[(128 + e) * 80 + h], wd = W1[(192 + e) * 80 + h];
    g_wkf[idx] = (f16)(wb - wc);
    g_wqf[idx] = (f16)wd;
    g_wsumT[idx] = (f16)(wa + wc);
  }
  if (idx < 4608) {
    int j = idx / 96, h = idx - j * 96;
    g_w2t[idx] = (h < 80 && j < 40) ? (f16)W2[h * 40 + j] : (f16)0.0f;
  }
}

__global__ __launch_bounds__(64, 3) void din_main(
    const float* __restrict__ query,
    const float* __restrict__ keys,
    const int*   __restrict__ keys_length,
    const float* __restrict__ b1,
    const float* __restrict__ b2,
    const float* __restrict__ W3,
    const float* __restrict__ b3,
    float* __restrict__ out)
{
  __shared__ __align__(16) f16 hs[HSLAB];   // 2,784 B (one wave per block)
  __shared__ float sSw[16];                 //     64 B

  const int lane = threadIdx.x;
  const int l15 = lane & 15;
  const int l4  = lane >> 4;

  const int b    = blockIdx.x >> 1;
  const int half = blockIdx.x & 1;
  const int mts  = half ? 7 : 0;
  const int mte  = half ? 13 : 7;

  const float* qp = query + (size_t)b * En;
  const float* kb = keys + (size_t)b * Tn * En;
  const int len = keys_length[b];
  const float b3v = b3[0];

  // ---- zero slab (cols 80..95 + pad must read 0.0 in L2 MFMAs) ----
  const f16x8 zf = (f16x8)(f16)0.0f;
  for (int i = lane * 8; i < HSLAB; i += 512) *(f16x8*)&hs[i] = zf;

  // ---- q fragments (f16) ----
  f16x8 qf0, qf1;
  {
    float4 qa = *(const float4*)(qp + l4 * 8);
    float4 qb = *(const float4*)(qp + l4 * 8 + 4);
    float4 qc = *(const float4*)(qp + 32 + l4 * 8);
    float4 qd = *(const float4*)(qp + 32 + l4 * 8 + 4);
    qf0 = pack8(qa, qb);
    qf1 = pack8(qc, qd);
  }

  // ---- qh[c] = b1[c] + q @ wsum[:,c] via VALU dot + shfl over l4 ----
  float qhv[5];
  #pragma unroll
  for (int n = 0; n < 5; ++n) {
    int c = n * 16 + l15;
    f16x8 ws0 = *(const f16x8*)&g_wsumT[c * 64 + l4 * 8];
    f16x8 ws1 = *(const f16x8*)&g_wsumT[c * 64 + 32 + l4 * 8];
    float p = 0.f;
    #pragma unroll
    for (int j = 0; j < 8; ++j)
      p += (float)qf0[j] * (float)ws0[j] + (float)qf1[j] * (float)ws1[j];
    p += __shfl_xor(p, 16, 64);
    p += __shfl_xor(p, 32, 64);
    qhv[n] = p + b1[c];
  }

  // ---- L1 B-fragments: Wb = wk + q*wqk (elementwise f16) ----
  f16x8 bf0[5], bf1[5];
  #pragma unroll
  for (int n = 0; n < 5; ++n) {
    int c = n * 16 + l15;
    bf0[n] = *(const f16x8*)&g_wkf[c * 64 + l4 * 8]
           + qf0 * *(const f16x8*)&g_wqf[c * 64 + l4 * 8];
    bf1[n] = *(const f16x8*)&g_wkf[c * 64 + 32 + l4 * 8]
           + qf1 * *(const f16x8*)&g_wqf[c * 64 + 32 + l4 * 8];
  }

  // ---- per-col constants for L2/L3 ----
  float b2v[3], w3v[3];
  #pragma unroll
  for (int n = 0; n < 3; ++n) {
    int c = n * 16 + l15;
    b2v[n] = (c < 40) ? b2[c] : 0.0f;
    w3v[n] = (c < 40) ? W3[c] : 0.0f;
  }

  float poolA[8] = {0,0,0,0,0,0,0,0};
  float poolB[8] = {0,0,0,0,0,0,0,0};

  // ---- prefetch first tile's keys rows ----
  float4 p0, p1, p2, p3;
  {
    int r = mts * 16 + l15; const float* kr = kb + (r < Tn ? r : Tn - 1) * 64;
    p0 = *(const float4*)(kr + l4 * 8);
    p1 = *(const float4*)(kr + l4 * 8 + 4);
    p2 = *(const float4*)(kr + 32 + l4 * 8);
    p3 = *(const float4*)(kr + 32 + l4 * 8 + 4);
  }

  for (int mt = mts; mt < mte; ++mt) {
    f16x8 ka = pack8(p0, p1);
    f16x8 kc = pack8(p2, p3);
    // issue next tile's loads under this tile's compute
    if (mt + 1 < mte) {
      int r = (mt + 1) * 16 + l15; const float* kr = kb + (r < Tn ? r : Tn - 1) * 64;
      p0 = *(const float4*)(kr + l4 * 8);
      p1 = *(const float4*)(kr + l4 * 8 + 4);
      p2 = *(const float4*)(kr + 32 + l4 * 8);
      p3 = *(const float4*)(kr + 32 + l4 * 8 + 4);
    }

    // L1 + sigmoid -> H slab, per n (acc liveness = 4)
    #pragma unroll
    for (int n = 0; n < 5; ++n) {
      f32x4 acc = {0.f, 0.f, 0.f, 0.f};
      acc = __builtin_amdgcn_mfma_f32_16x16x32_f16(ka, bf0[n], acc, 0, 0, 0);
      acc = __builtin_amdgcn_mfma_f32_16x16x32_f16(kc, bf1[n], acc, 0, 0, 0);
      int c = n * 16 + l15;
      #pragma unroll
      for (int i = 0; i < 4; ++i)
        hs[(l4 * 4 + i) * HS_W + c] = (f16)fsig(acc[i] + qhv[n]);
    }
    // H^T A-frags
    f16x8 aH0 = *(const f16x8*)&hs[l15 * HS_W + l4 * 8];
    f16x8 aH1 = *(const f16x8*)&hs[l15 * HS_W + 32 + l4 * 8];
    f16x8 aH2 = *(const f16x8*)&hs[l15 * HS_W + 64 + l4 * 8];

    // L2 (B-frags from global g_w2t, L1-cache-hot) + sigmoid + W3 dot
    float sc[4] = {0.f, 0.f, 0.f, 0.f};
    #pragma unroll
    for (int n = 0; n < 3; ++n) {
      int c = n * 16 + l15;
      f32x4 acc = {0.f, 0.f, 0.f, 0.f};
      acc = __builtin_amdgcn_mfma_f32_16x16x32_f16(aH0, *(const f16x8*)&g_w2t[c * 96 + l4 * 8], acc, 0, 0, 0);
      acc = __builtin_amdgcn_mfma_f32_16x16x32_f16(aH1, *(const f16x8*)&g_w2t[c * 96 + 32 + l4 * 8], acc, 0, 0, 0);
      acc = __builtin_amdgcn_mfma_f32_16x16x32_f16(aH2, *(const f16x8*)&g_w2t[c * 96 + 64 + l4 * 8], acc, 0, 0, 0);
      #pragma unroll
      for (int i = 0; i < 4; ++i)
        sc[i] += fsig(acc[i] + b2v[n]) * w3v[n];
    }
    // reduce score over the 16 cols (l15) via DPP row_ror — no LDS pipe
    #pragma unroll
    for (int i = 0; i < 4; ++i) sc[i] = row16_sum(sc[i]);
    if (l15 == 0) {
      #pragma unroll
      for (int i = 0; i < 4; ++i) {
        int rr = mt * 16 + l4 * 4 + i;
        sSw[l4 * 4 + i] = (rr < len) ? sc[i] + b3v : 0.0f;
      }
    }
    // broadcast this lane's row score (same-wave LDS, in-order per wave)
    float sv = sSw[l15];
    #pragma unroll
    for (int j = 0; j < 8; ++j) {
      poolA[j] += sv * (float)ka[j];
      poolB[j] += sv * (float)kc[j];
    }
  }

  // ---- reduce pooling over the 16 rows (l15) via DPP row_ror ----
  #pragma unroll
  for (int j = 0; j < 8; ++j) {
    poolA[j] = row16_sum(poolA[j]);
    poolB[j] = row16_sum(poolB[j]);
  }
  if (l15 == 0) {
    float* ob = out + (size_t)b * En;
    #pragma unroll
    for (int j = 0; j < 8; ++j) {
      atomicAdd(&ob[l4 * 8 + j], poolA[j]);
      atomicAdd(&ob[32 + l4 * 8 + j], poolB[j]);
    }
  }
}

extern "C" void kernel_launch(void* const* d_in, const int* in_sizes, int n_in,
                              void* d_out, int out_size, void* d_ws, size_t ws_size,
                              hipStream_t stream) {
  const float* query       = (const float*)d_in[0];
  const float* keys        = (const float*)d_in[1];
  const int*   keys_length = (const int*)d_in[2];
  const float* W1 = (const float*)d_in[3];
  const float* b1 = (const float*)d_in[4];
  const float* W2 = (const float*)d_in[5];
  const float* b2 = (const float*)d_in[6];
  const float* W3 = (const float*)d_in[7];
  const float* b3 = (const float*)d_in[8];
  float* out = (float*)d_out;

  hipMemsetAsync(out, 0, (size_t)Bn * En * sizeof(float), stream);
  hipLaunchKernelGGL(din_prep, dim3(20), dim3(256), 0, stream, W1, W2);
  hipLaunchKernelGGL(din_main, dim3(Bn * 2), dim3(64), 0, stream,
                     query, keys, keys_length, b1, b2, W3, b3, out);
}